// Round 2
// baseline (205.475 us; speedup 1.0000x reference)
//
#include <hip/hip_runtime.h>

#define EPSF 1e-6f

// ---------------------------------------------------------------------------
// DPP full-wave (64-lane) sum. After this, lane 63 holds the wave total.
// Classic gfx9 sequence: row_shr 1/2/4/8 (intra-row-of-16 prefix sums), then
// row_bcast:15 (lane15->row1, lane47->row3) and row_bcast:31 (lane31->rows2,3).
// All VALU-pipe — no ds_bpermute, no LDS traffic.
// ---------------------------------------------------------------------------
__device__ __forceinline__ float wave_sum_to_lane63(float x) {
  x += __int_as_float(__builtin_amdgcn_update_dpp(0, __float_as_int(x), 0x111, 0xf, 0xf, true));  // row_shr:1
  x += __int_as_float(__builtin_amdgcn_update_dpp(0, __float_as_int(x), 0x112, 0xf, 0xf, true));  // row_shr:2
  x += __int_as_float(__builtin_amdgcn_update_dpp(0, __float_as_int(x), 0x114, 0xf, 0xf, true));  // row_shr:4
  x += __int_as_float(__builtin_amdgcn_update_dpp(0, __float_as_int(x), 0x118, 0xf, 0xf, true));  // row_shr:8
  x += __int_as_float(__builtin_amdgcn_update_dpp(0, __float_as_int(x), 0x142, 0xa, 0xf, false)); // row_bcast:15
  x += __int_as_float(__builtin_amdgcn_update_dpp(0, __float_as_int(x), 0x143, 0xc, 0xf, false)); // row_bcast:31
  return x;
}

// ---------------------------------------------------------------------------
// Kernel 1: streaming reduction. For each batch b, block writes 66 partials:
//   [0]           = sum pred[b,0,:] * gt[b,0,:]            (bg inter)
//   [1 + p*7 + g] = sum pred[b,p+1,:] * gt[b,g+1,:]        (fg inter)
//   [50 + s]      = sum pred[b,s,:]                        (pred sums)
//   [58 + s]      = sum gt[b,s,:]                          (gt sums)
// Each block writes its own scratch row (no atomics, no zero-init needed).
// ---------------------------------------------------------------------------
__global__ __launch_bounds__(256, 4) void msl_accum(const float* __restrict__ pred,
                                                    const float* __restrict__ gt,
                                                    float* __restrict__ part,
                                                    int HW, int HW4) {
  const int b = blockIdx.y;
  const size_t base = (size_t)b * 8 * (size_t)HW;
  const float* P = pred + base;
  const float* G = gt + base;

  float a_bg = 0.0f;
  float af[7][7];
  float sp[8], sg[8];
#pragma unroll
  for (int p = 0; p < 7; ++p)
#pragma unroll
    for (int g = 0; g < 7; ++g) af[p][g] = 0.0f;
#pragma unroll
  for (int s = 0; s < 8; ++s) { sp[s] = 0.0f; sg[s] = 0.0f; }

  const int stride = blockDim.x * gridDim.x;
  for (int i = blockIdx.x * blockDim.x + threadIdx.x; i < HW4; i += stride) {
    float4 pv[8], gv[8];
#pragma unroll
    for (int s = 0; s < 8; ++s)
      pv[s] = ((const float4*)(P + (size_t)s * HW))[i];
#pragma unroll
    for (int s = 0; s < 8; ++s)
      gv[s] = ((const float4*)(G + (size_t)s * HW))[i];

#pragma unroll
    for (int s = 0; s < 8; ++s) {
      sp[s] += (pv[s].x + pv[s].y) + (pv[s].z + pv[s].w);
      sg[s] += (gv[s].x + gv[s].y) + (gv[s].z + gv[s].w);
    }
    a_bg += pv[0].x * gv[0].x + pv[0].y * gv[0].y +
            pv[0].z * gv[0].z + pv[0].w * gv[0].w;
#pragma unroll
    for (int p = 0; p < 7; ++p)
#pragma unroll
      for (int g = 0; g < 7; ++g)
        af[p][g] += pv[p + 1].x * gv[g + 1].x + pv[p + 1].y * gv[g + 1].y +
                    pv[p + 1].z * gv[g + 1].z + pv[p + 1].w * gv[g + 1].w;
  }

  float v[66];
  v[0] = a_bg;
#pragma unroll
  for (int p = 0; p < 7; ++p)
#pragma unroll
    for (int g = 0; g < 7; ++g) v[1 + p * 7 + g] = af[p][g];
#pragma unroll
  for (int s = 0; s < 8; ++s) { v[50 + s] = sp[s]; v[58 + s] = sg[s]; }

  __shared__ float red[4][66];
  const int wave = threadIdx.x >> 6;
  const int lane = threadIdx.x & 63;
#pragma unroll
  for (int k = 0; k < 66; ++k) {
    float x = wave_sum_to_lane63(v[k]);
    if (lane == 63) red[wave][k] = x;   // exec-masked store, 1 DS instr per k
  }
  __syncthreads();

  const int row = blockIdx.y * gridDim.x + blockIdx.x;
  if (threadIdx.x < 66) {
    float s = red[0][threadIdx.x] + red[1][threadIdx.x] +
              red[2][threadIdx.x] + red[3][threadIdx.x];
    part[row * 66 + threadIdx.x] = s;   // private row — no atomic, no pre-zero
  }
}

// ---------------------------------------------------------------------------
// Kernel 2: finalize. One block, 32 lanes per batch.
// Sums the RPB per-block partial rows, builds dice[p][g], then computes the
// optimal-assignment VALUE via bitmask DP over used-pred-slot sets (the
// Hungarian matching is only consumed through the sum of matched dice, so the
// optimum value is all we need). dp stride 130 breaks LDS bank conflicts.
// ---------------------------------------------------------------------------
__global__ __launch_bounds__(1024) void msl_final(const float* __restrict__ part,
                                                  const int* __restrict__ nobj,
                                                  float* __restrict__ out,
                                                  int B, int RPB) {
  __shared__ float a[32][68];
  __shared__ float dp[32][130];
  __shared__ float dice[32][52];
  __shared__ float r_bg[32];
  __shared__ float r_ds[32];
  __shared__ int   r_n[32];

  const int batch = threadIdx.x >> 5;
  const int lane  = threadIdx.x & 31;
  const bool act  = (batch < B);

  if (act) {
    for (int k = lane; k < 66; k += 32) {
      float s = 0.0f;
      for (int r = 0; r < RPB; ++r) s += part[(batch * RPB + r) * 66 + k];
      a[batch][k] = s;
    }
  }
  __syncthreads();

  if (act) {
    for (int k = lane; k < 49; k += 32) {
      int p = k / 7, g = k % 7;
      dice[batch][k] = (2.0f * a[batch][1 + k] + EPSF) /
                       (a[batch][51 + p] + a[batch][59 + g] + EPSF);
    }
    if (lane == 0) {
      float u = a[batch][50] + a[batch][58];
      r_bg[batch] = 1.0f - (2.0f * a[batch][0] + EPSF) / (u + EPSF);
      int n = nobj[batch];
      n = n < 0 ? 0 : (n > 7 ? 7 : n);
      r_n[batch] = n;
      r_ds[batch] = 0.0f;
      dp[batch][0] = 0.0f;
    }
  }
  __syncthreads();
  const int n = act ? r_n[batch] : 0;

  // DP layers: masks of popcount c depend only on layer c-1; lane-parallel.
  for (int c = 1; c <= 7; ++c) {
    if (act && c <= n) {
      for (int mask = lane; mask < 128; mask += 32) {
        if (__popc(mask) == c) {
          float best = -1e30f;
#pragma unroll
          for (int r = 0; r < 7; ++r) {
            if (mask & (1 << r)) {
              float cand = dp[batch][mask ^ (1 << r)] + dice[batch][r * 7 + (c - 1)];
              best = fmaxf(best, cand);
            }
          }
          dp[batch][mask] = best;
        }
      }
    }
    __syncthreads();
  }

  float best = -1e30f;
  if (act && n > 0) {
    for (int mask = lane; mask < 128; mask += 32)
      if (__popc(mask) == n) best = fmaxf(best, dp[batch][mask]);
  }
#pragma unroll
  for (int off = 16; off > 0; off >>= 1)
    best = fmaxf(best, __shfl_down(best, off, 32));
  if (act && lane == 0 && n > 0) r_ds[batch] = best;
  __syncthreads();

  if (threadIdx.x == 0) {
    float bg = 0.0f, ds = 0.0f;
    int cnt = 0;
    for (int b = 0; b < B; ++b) { bg += r_bg[b]; ds += r_ds[b]; cnt += r_n[b]; }
    float fg = cnt > 0 ? ((float)cnt - ds) / (float)cnt : 0.0f;
    out[0] = bg / (float)B + fg;
  }
}

// ---------------------------------------------------------------------------
extern "C" void kernel_launch(void* const* d_in, const int* in_sizes, int n_in,
                              void* d_out, int out_size, void* d_ws, size_t ws_size,
                              hipStream_t stream) {
  const float* pred = (const float*)d_in[0];
  const float* gt   = (const float*)d_in[1];
  const int*   nobj = (const int*)d_in[2];
  float* out = (float*)d_out;

  const int B  = in_sizes[2];              // 32
  const int HW = in_sizes[0] / (B * 8);    // 65536
  const int HW4 = HW / 4;

  float* part = (float*)d_ws;              // B * 32 blocks * 66 floats = 270 KB

  const int blocksPerBatch = 32;           // 1024 blocks, 2 f4-iters/thread
  msl_accum<<<dim3(blocksPerBatch, B), dim3(256), 0, stream>>>(pred, gt, part, HW, HW4);

  msl_final<<<dim3(1), dim3(32 * B), 0, stream>>>(part, nobj, out, B, blocksPerBatch);
}

// Round 3
// 167.984 us; speedup vs baseline: 1.2232x; 1.2232x over previous
//
#include <hip/hip_runtime.h>

#define EPSF 1e-6f

// ---------------------------------------------------------------------------
// DPP full-wave (64-lane) sum. After this, lane 63 holds the wave total.
// row_shr 1/2/4/8 (intra-row-of-16), then row_bcast:15 and row_bcast:31.
// All VALU-pipe — no ds_bpermute, no LDS traffic.
// ---------------------------------------------------------------------------
__device__ __forceinline__ float wave_sum_to_lane63(float x) {
  x += __int_as_float(__builtin_amdgcn_update_dpp(0, __float_as_int(x), 0x111, 0xf, 0xf, true));  // row_shr:1
  x += __int_as_float(__builtin_amdgcn_update_dpp(0, __float_as_int(x), 0x112, 0xf, 0xf, true));  // row_shr:2
  x += __int_as_float(__builtin_amdgcn_update_dpp(0, __float_as_int(x), 0x114, 0xf, 0xf, true));  // row_shr:4
  x += __int_as_float(__builtin_amdgcn_update_dpp(0, __float_as_int(x), 0x118, 0xf, 0xf, true));  // row_shr:8
  x += __int_as_float(__builtin_amdgcn_update_dpp(0, __float_as_int(x), 0x142, 0xa, 0xf, false)); // row_bcast:15
  x += __int_as_float(__builtin_amdgcn_update_dpp(0, __float_as_int(x), 0x143, 0xc, 0xf, false)); // row_bcast:31
  return x;
}

// ---------------------------------------------------------------------------
// Kernel 1: streaming reduction. For each batch b, block writes 66 partials:
//   [0]           = sum pred[b,0,:] * gt[b,0,:]            (bg inter)
//   [1 + p*7 + g] = sum pred[b,p+1,:] * gt[b,g+1,:]        (fg inter)
//   [50 + s]      = sum pred[b,s,:]                        (pred sums)
//   [58 + s]      = sum gt[b,s,:]                          (gt sums)
// Each block writes a private scratch row (no atomics, no zero-init).
// NOTE: no waves-per-EU clamp — 66 live accumulators need ~120 VGPRs; a
// tighter bound forces catastrophic scratch spills (measured round 2: 85 MB
// scratch writes, 64 VGPRs, 1.5-3x slower).
// ---------------------------------------------------------------------------
__global__ __launch_bounds__(256) void msl_accum(const float* __restrict__ pred,
                                                 const float* __restrict__ gt,
                                                 float* __restrict__ part,
                                                 int HW, int HW4) {
  const int b = blockIdx.y;
  const size_t base = (size_t)b * 8 * (size_t)HW;
  const float* P = pred + base;
  const float* G = gt + base;

  float a_bg = 0.0f;
  float af[7][7];
  float sp[8], sg[8];
#pragma unroll
  for (int p = 0; p < 7; ++p)
#pragma unroll
    for (int g = 0; g < 7; ++g) af[p][g] = 0.0f;
#pragma unroll
  for (int s = 0; s < 8; ++s) { sp[s] = 0.0f; sg[s] = 0.0f; }

  const int stride = blockDim.x * gridDim.x;
  for (int i = blockIdx.x * blockDim.x + threadIdx.x; i < HW4; i += stride) {
    // Keep the 8 pred vectors live; stream gt vectors through one at a time.
    // 9 live float4 (36 VGPR) instead of 16 (64 VGPR) + 66 accumulators.
    float4 pv[8];
#pragma unroll
    for (int s = 0; s < 8; ++s)
      pv[s] = ((const float4*)(P + (size_t)s * HW))[i];
#pragma unroll
    for (int s = 0; s < 8; ++s)
      sp[s] += (pv[s].x + pv[s].y) + (pv[s].z + pv[s].w);

#pragma unroll
    for (int s = 0; s < 8; ++s) {
      float4 gv = ((const float4*)(G + (size_t)s * HW))[i];
      sg[s] += (gv.x + gv.y) + (gv.z + gv.w);
      if (s == 0) {
        a_bg += pv[0].x * gv.x + pv[0].y * gv.y + pv[0].z * gv.z + pv[0].w * gv.w;
      } else {
#pragma unroll
        for (int p = 0; p < 7; ++p)
          af[p][s - 1] += pv[p + 1].x * gv.x + pv[p + 1].y * gv.y +
                          pv[p + 1].z * gv.z + pv[p + 1].w * gv.w;
      }
    }
  }

  float v[66];
  v[0] = a_bg;
#pragma unroll
  for (int p = 0; p < 7; ++p)
#pragma unroll
    for (int g = 0; g < 7; ++g) v[1 + p * 7 + g] = af[p][g];
#pragma unroll
  for (int s = 0; s < 8; ++s) { v[50 + s] = sp[s]; v[58 + s] = sg[s]; }

  __shared__ float red[4][66];
  const int wave = threadIdx.x >> 6;
  const int lane = threadIdx.x & 63;
#pragma unroll
  for (int k = 0; k < 66; ++k) {
    float x = wave_sum_to_lane63(v[k]);
    if (lane == 63) red[wave][k] = x;   // exec-masked store, 1 DS instr per k
  }
  __syncthreads();

  const int row = blockIdx.y * gridDim.x + blockIdx.x;
  if (threadIdx.x < 66) {
    float s = red[0][threadIdx.x] + red[1][threadIdx.x] +
              red[2][threadIdx.x] + red[3][threadIdx.x];
    part[row * 66 + threadIdx.x] = s;   // private row — no atomic, no pre-zero
  }
}

// ---------------------------------------------------------------------------
// Kernel 2: finalize. One block, 32 lanes per batch.
// Sums the RPB per-block partial rows, builds dice[p][g], then computes the
// optimal-assignment VALUE via bitmask DP over used-pred-slot sets (the
// Hungarian matching is only consumed through the sum of matched dice, so
// the optimum value is all we need). dp stride 130 breaks LDS bank conflicts.
// ---------------------------------------------------------------------------
__global__ __launch_bounds__(1024) void msl_final(const float* __restrict__ part,
                                                  const int* __restrict__ nobj,
                                                  float* __restrict__ out,
                                                  int B, int RPB) {
  __shared__ float a[32][68];
  __shared__ float dp[32][130];
  __shared__ float dice[32][52];
  __shared__ float r_bg[32];
  __shared__ float r_ds[32];
  __shared__ int   r_n[32];

  const int batch = threadIdx.x >> 5;
  const int lane  = threadIdx.x & 31;
  const bool act  = (batch < B);

  if (act) {
    for (int k = lane; k < 66; k += 32) {
      float s = 0.0f;
#pragma unroll 4
      for (int r = 0; r < RPB; ++r) s += part[(batch * RPB + r) * 66 + k];
      a[batch][k] = s;
    }
  }
  __syncthreads();

  if (act) {
    for (int k = lane; k < 49; k += 32) {
      int p = k / 7, g = k % 7;
      dice[batch][k] = (2.0f * a[batch][1 + k] + EPSF) /
                       (a[batch][51 + p] + a[batch][59 + g] + EPSF);
    }
    if (lane == 0) {
      float u = a[batch][50] + a[batch][58];
      r_bg[batch] = 1.0f - (2.0f * a[batch][0] + EPSF) / (u + EPSF);
      int n = nobj[batch];
      n = n < 0 ? 0 : (n > 7 ? 7 : n);
      r_n[batch] = n;
      r_ds[batch] = 0.0f;
      dp[batch][0] = 0.0f;
    }
  }
  __syncthreads();
  const int n = act ? r_n[batch] : 0;

  // DP layers: masks of popcount c depend only on layer c-1; lane-parallel.
  for (int c = 1; c <= 7; ++c) {
    if (act && c <= n) {
      for (int mask = lane; mask < 128; mask += 32) {
        if (__popc(mask) == c) {
          float best = -1e30f;
#pragma unroll
          for (int r = 0; r < 7; ++r) {
            if (mask & (1 << r)) {
              float cand = dp[batch][mask ^ (1 << r)] + dice[batch][r * 7 + (c - 1)];
              best = fmaxf(best, cand);
            }
          }
          dp[batch][mask] = best;
        }
      }
    }
    __syncthreads();
  }

  float best = -1e30f;
  if (act && n > 0) {
    for (int mask = lane; mask < 128; mask += 32)
      if (__popc(mask) == n) best = fmaxf(best, dp[batch][mask]);
  }
#pragma unroll
  for (int off = 16; off > 0; off >>= 1)
    best = fmaxf(best, __shfl_down(best, off, 32));
  if (act && lane == 0 && n > 0) r_ds[batch] = best;
  __syncthreads();

  if (threadIdx.x == 0) {
    float bg = 0.0f, ds = 0.0f;
    int cnt = 0;
    for (int b = 0; b < B; ++b) { bg += r_bg[b]; ds += r_ds[b]; cnt += r_n[b]; }
    float fg = cnt > 0 ? ((float)cnt - ds) / (float)cnt : 0.0f;
    out[0] = bg / (float)B + fg;
  }
}

// ---------------------------------------------------------------------------
extern "C" void kernel_launch(void* const* d_in, const int* in_sizes, int n_in,
                              void* d_out, int out_size, void* d_ws, size_t ws_size,
                              hipStream_t stream) {
  const float* pred = (const float*)d_in[0];
  const float* gt   = (const float*)d_in[1];
  const int*   nobj = (const int*)d_in[2];
  float* out = (float*)d_out;

  const int B  = in_sizes[2];              // 32
  const int HW = in_sizes[0] / (B * 8);    // 65536
  const int HW4 = HW / 4;

  float* part = (float*)d_ws;              // B * 16 blocks * 66 floats = 135 KB

  // 16 blocks/batch = 512 blocks = 2 blocks/CU; 4 f4-iters/thread amortizes
  // the 66x6-DPP tail over 2x more main-loop work than 32 blocks/batch.
  const int blocksPerBatch = 16;
  msl_accum<<<dim3(blocksPerBatch, B), dim3(256), 0, stream>>>(pred, gt, part, HW, HW4);

  msl_final<<<dim3(1), dim3(32 * B), 0, stream>>>(part, nobj, out, B, blocksPerBatch);
}